// Round 5
// baseline (145.408 us; speedup 1.0000x reference)
//
#include <hip/hip_runtime.h>

#define NN 512
#define DD 128
#define HH 256
#define NBLK 256
#define NTHR 512

__device__ __forceinline__ float dot4(float4 a, float4 b) {
    return a.x * b.x + a.y * b.y + a.z * b.z + a.w * b.w;
}

// Monotonic grid barrier: each block adds 1; wait until count >= target.
// Counter memset to 0 before each launch. Timeout guard -> visible failure,
// never a hang.
__device__ __forceinline__ void gbar(unsigned* cnt, unsigned target) {
    __syncthreads();
    if (threadIdx.x == 0) {
        __threadfence();
        __hip_atomic_fetch_add(cnt, 1u, __ATOMIC_RELEASE, __HIP_MEMORY_SCOPE_AGENT);
        int tries = 0;
        while (__hip_atomic_load(cnt, __ATOMIC_ACQUIRE, __HIP_MEMORY_SCOPE_AGENT) < target) {
            __builtin_amdgcn_s_sleep(8);
            if (++tries > (1 << 20)) break;
        }
        __threadfence();
    }
    __syncthreads();
}

template <int MODE>
__device__ __forceinline__ void stage(const float* __restrict__ A,
                                      const float* __restrict__ WT,
                                      const float* __restrict__ bias,
                                      const float* __restrict__ rowsum,
                                      float* __restrict__ C,
                                      float* smem, int b, int t) {
    float* As = smem;              // [8][260]
    float* redS = smem + 8 * 260;  // [4][8][64]
    const int i0 = (b & 63) * 8;
    const int k0 = (b >> 6) * 64;
    {
        const int f = t * 4;
        const int r = f >> 8;
        const int c = f & 255;
        *(float4*)&As[r * 260 + c] = *(const float4*)&A[(i0 + r) * HH + c];
    }
    __syncthreads();
    const int hph = t >> 7;
    const int r = (t >> 4) & 7;
    const int kq = t & 15;
    const float* wt = WT + k0 + kq * 4;
    const float* as = As + r * 260 + hph * 64;
    float4 ac0 = {0.f, 0.f, 0.f, 0.f};
    float4 ac1 = {0.f, 0.f, 0.f, 0.f};
    #pragma unroll 8
    for (int hh = 0; hh < 64; hh += 2) {
        float a0 = as[hh];
        float a1 = as[hh + 1];
        float4 w0 = *(const float4*)&wt[(hph * 64 + hh) * HH];
        float4 w1 = *(const float4*)&wt[(hph * 64 + hh + 1) * HH];
        ac0.x += a0 * w0.x; ac0.y += a0 * w0.y; ac0.z += a0 * w0.z; ac0.w += a0 * w0.w;
        ac1.x += a1 * w1.x; ac1.y += a1 * w1.y; ac1.z += a1 * w1.z; ac1.w += a1 * w1.w;
    }
    ac0.x += ac1.x; ac0.y += ac1.y; ac0.z += ac1.z; ac0.w += ac1.w;
    *(float4*)&redS[(hph * 8 + r) * 64 + kq * 4] = ac0;
    __syncthreads();
    if (hph == 0) {
        #pragma unroll
        for (int p = 1; p < 4; ++p) {
            float4 o = *(const float4*)&redS[(p * 8 + r) * 64 + kq * 4];
            ac0.x += o.x; ac0.y += o.y; ac0.z += o.z; ac0.w += o.w;
        }
        const int k = k0 + kq * 4;
        float4 bv = *(const float4*)&bias[k];
        if (MODE == 0) {
            const float rs = rowsum[i0 + r];
            const float inv = 1.0f / (float)NN;
            ac0.x = (ac0.x + bv.x * rs) * inv;
            ac0.y = (ac0.y + bv.y * rs) * inv;
            ac0.z = (ac0.z + bv.z * rs) * inv;
            ac0.w = (ac0.w + bv.w * rs) * inv;
        } else if (MODE == 1) {
            ac0.x = fmaxf(ac0.x + bv.x, 0.f);
            ac0.y = fmaxf(ac0.y + bv.y, 0.f);
            ac0.z = fmaxf(ac0.z + bv.z, 0.f);
            ac0.w = fmaxf(ac0.w + bv.w, 0.f);
        } else {
            ac0.x += bv.x; ac0.y += bv.y; ac0.z += bv.z; ac0.w += bv.w;
        }
        *(float4*)&C[(i0 + r) * HH + k] = ac0;
    }
}

__global__ __launch_bounds__(NTHR, 2) void k_fused(const float* __restrict__ x,
                                                   const float* __restrict__ adj,
                                                   const float* __restrict__ W1,
                                                   const float* __restrict__ b1,
                                                   const float* __restrict__ W2,
                                                   const float* __restrict__ b2,
                                                   const float* __restrict__ Wo1,
                                                   const float* __restrict__ bo1,
                                                   const float* __restrict__ Wo2,
                                                   const float* __restrict__ bo2,
                                                   float* __restrict__ out,
                                                   float* __restrict__ ws) {
    __shared__ __align__(16) float smem[4608];

    float* W2T    = ws;             // [256][256]
    float* Wo1T   = ws + 65536;
    float* Wo2T   = ws + 131072;
    float* pa     = ws + 196608;    // [512][256]
    float* pbb    = ws + 327680;    // [512][256]  (pb + b1)
    float* Tsum   = ws + 458752;    // [512][256]
    float* rowsum = ws + 589824;    // [512]
    float* pred   = ws + 590336;    // [512][256]
    float* h2     = ws + 721408;    // [512][256]
    unsigned* bar = (unsigned*)(ws + 852480);

    const int b = blockIdx.x;
    const int t = threadIdx.x;

    // ---------------- Phase A0: transpose W2/Wo1/Wo2 (blocks 0..47) --------
    if (b < 48) {
        const int m = b >> 4, tile = b & 15;
        const float* src = (m == 0) ? W2 : (m == 1) ? Wo1 : Wo2;
        float* dst = (m == 0) ? W2T : (m == 1) ? Wo1T : Wo2T;
        const int sr0 = (tile >> 2) * 64;
        const int sc0 = (tile & 3) * 64;
        float (*tl)[68] = (float(*)[68])smem;
        const int rr = t >> 4;          // 0..31
        const int cc = (t & 15) * 4;
        #pragma unroll
        for (int it = 0; it < 2; ++it) {
            const int row = rr + 32 * it;
            float4 v = *(const float4*)&src[(sr0 + row) * HH + sc0 + cc];
            tl[row][cc + 0] = v.x;
            tl[row][cc + 1] = v.y;
            tl[row][cc + 2] = v.z;
            tl[row][cc + 3] = v.w;
        }
        __syncthreads();
        #pragma unroll
        for (int it = 0; it < 2; ++it) {
            const int lc = rr + 32 * it;
            float4 o;
            o.x = tl[cc + 0][lc];
            o.y = tl[cc + 1][lc];
            o.z = tl[cc + 2][lc];
            o.w = tl[cc + 3][lc];
            *(float4*)&dst[(sc0 + lc) * HH + sr0 + cc] = o;
        }
        __syncthreads();
    }

    // ---------------- Phase A1: pa / pbb (all blocks, 2 rows each) ---------
    {
        float (*xs)[DD] = (float(*)[DD])smem;
        const int i0 = b * 2;
        if (t < 64) {
            const int f = t * 4;
            *(float4*)&xs[f >> 7][f & 127] = *(const float4*)&x[i0 * DD + f];
        }
        __syncthreads();
        const int r = t >> 8;
        const int h = t & 255;
        const float4* w4 = (const float4*)(W1 + h * (2 * DD));
        const float4* xv4 = (const float4*)&xs[r][0];
        float a = 0.f, bb_ = 0.f;
        #pragma unroll 8
        for (int d4 = 0; d4 < 32; ++d4) {
            float4 xv = xv4[d4];
            a   += dot4(w4[d4], xv);
            bb_ += dot4(w4[d4 + 32], xv);
        }
        pa[(i0 + r) * HH + h] = a;
        pbb[(i0 + r) * HH + h] = bb_ + b1[h];
    }
    gbar(bar, NBLK);

    // ---------------- Phase B: Tsum + rowsum -------------------------------
    {
        float* adjs = smem;             // [4][516]
        float* redT = smem + 4 * 516;   // [3][4][128]
        const int hb = b >> 7;
        const int itile = b & 127;
        const int i0 = itile * 4;
        {
            const int f = t * 4;
            const int r = f >> 9;
            const int c = f & 511;
            *(float4*)&adjs[r * 516 + c] = *(const float4*)&adj[(i0 + r) * NN + c];
        }
        const int jq = t >> 7;
        const int hl = t & 127;
        const int h = hb * 128 + hl;
        float pbv[4], acc[4] = {0.f, 0.f, 0.f, 0.f};
        #pragma unroll
        for (int r = 0; r < 4; ++r) pbv[r] = pbb[(i0 + r) * HH + h];
        __syncthreads();
        const float* pac = pa + (jq * 128) * HH + h;
        #pragma unroll 2
        for (int j = 0; j < 128; j += 4) {
            float p0 = pac[(j + 0) * HH];
            float p1 = pac[(j + 1) * HH];
            float p2 = pac[(j + 2) * HH];
            float p3 = pac[(j + 3) * HH];
            #pragma unroll
            for (int r = 0; r < 4; ++r) {
                float4 a4 = *(const float4*)&adjs[r * 516 + jq * 128 + j];
                acc[r] += a4.x * fmaxf(p0 + pbv[r], 0.f);
                acc[r] += a4.y * fmaxf(p1 + pbv[r], 0.f);
                acc[r] += a4.z * fmaxf(p2 + pbv[r], 0.f);
                acc[r] += a4.w * fmaxf(p3 + pbv[r], 0.f);
            }
        }
        if (jq) {
            #pragma unroll
            for (int r = 0; r < 4; ++r) redT[(jq - 1) * 512 + r * 128 + hl] = acc[r];
        }
        __syncthreads();
        if (jq == 0) {
            #pragma unroll
            for (int r = 0; r < 4; ++r)
                Tsum[(i0 + r) * HH + h] = acc[r] + redT[r * 128 + hl]
                                        + redT[512 + r * 128 + hl]
                                        + redT[1024 + r * 128 + hl];
        }
        if (hb == 0 && t < 256) {
            const int r = t >> 6, l = t & 63;
            float s = 0.f;
            #pragma unroll
            for (int m2 = 0; m2 < 8; ++m2) s += adjs[r * 516 + l + 64 * m2];
            #pragma unroll
            for (int off = 32; off > 0; off >>= 1) s += __shfl_down(s, off, 64);
            if (l == 0) rowsum[i0 + r] = s;
        }
    }
    gbar(bar, 2 * NBLK);

    // ---------------- P3: pred = (Tsum@W2T + b2*rowsum)/N ------------------
    stage<0>(Tsum, W2T, b2, rowsum, pred, smem, b, t);
    gbar(bar, 3 * NBLK);

    // ---------------- P4: h2 = relu(pred@Wo1T + bo1) -----------------------
    stage<1>(pred, Wo1T, bo1, rowsum, h2, smem, b, t);
    gbar(bar, 4 * NBLK);

    // ---------------- P5: out = h2@Wo2T + bo2 ------------------------------
    stage<2>(h2, Wo2T, bo2, rowsum, out, smem, b, t);
}

extern "C" void kernel_launch(void* const* d_in, const int* in_sizes, int n_in,
                              void* d_out, int out_size, void* d_ws, size_t ws_size,
                              hipStream_t stream) {
    const float* x   = (const float*)d_in[0];
    const float* adj = (const float*)d_in[1];
    const float* W1  = (const float*)d_in[2];
    const float* b1  = (const float*)d_in[3];
    const float* W2  = (const float*)d_in[4];
    const float* b2  = (const float*)d_in[5];
    const float* Wo1 = (const float*)d_in[6];
    const float* bo1 = (const float*)d_in[7];
    const float* Wo2 = (const float*)d_in[8];
    const float* bo2 = (const float*)d_in[9];
    float* out = (float*)d_out;
    float* ws  = (float*)d_ws;

    hipMemsetAsync(ws + 852480, 0, 64, stream);
    k_fused<<<NBLK, NTHR, 0, stream>>>(x, adj, W1, b1, W2, b2, Wo1, bo1, Wo2,
                                       bo2, out, ws);
}

// Round 6
// 50.245 us; speedup vs baseline: 2.8940x; 2.8940x over previous
//
#include <hip/hip_runtime.h>

#define NN 512
#define DD 128
#define HH 256

__device__ __forceinline__ float dot4(float4 a, float4 b) {
    return a.x * b.x + a.y * b.y + a.z * b.z + a.w * b.w;
}

// K1: pa = x@Wa^T, pbb = x@Wb^T + b1.  256 blocks x 256 threads, 2 rows/block.
__global__ __launch_bounds__(256) void k1_papb(const float* __restrict__ x,
                                               const float* __restrict__ W1,
                                               const float* __restrict__ b1,
                                               float* __restrict__ pa,
                                               float* __restrict__ pbb) {
    __shared__ float xs[2][DD];
    const int b = blockIdx.x;
    const int t = threadIdx.x;
    const int i0 = b * 2;
    if (t < 64) {
        const int f = t * 4;
        *(float4*)&xs[f >> 7][f & 127] = *(const float4*)&x[i0 * DD + f];
    }
    __syncthreads();
    const int h = t;
    const float4* w4 = (const float4*)(W1 + h * (2 * DD));
    const float4* x0 = (const float4*)&xs[0][0];
    const float4* x1 = (const float4*)&xs[1][0];
    float a0 = 0.f, a1 = 0.f, c0 = 0.f, c1 = 0.f;
    #pragma unroll 8
    for (int d4 = 0; d4 < DD / 4; ++d4) {
        float4 wa = w4[d4];
        float4 wb = w4[d4 + 32];
        float4 v0 = x0[d4];
        float4 v1 = x1[d4];
        a0 += dot4(wa, v0);
        a1 += dot4(wa, v1);
        c0 += dot4(wb, v0);
        c1 += dot4(wb, v1);
    }
    const float bb = b1[h];
    pa[i0 * HH + h] = a0;
    pa[(i0 + 1) * HH + h] = a1;
    pbb[i0 * HH + h] = c0 + bb;
    pbb[(i0 + 1) * HH + h] = c1 + bb;
}

// K2: everything after pa, fully row-local. 256 blocks x 512 threads, 2 rows.
__global__ __launch_bounds__(512, 2) void k2_rest(const float* __restrict__ adj,
                                                  const float* __restrict__ pa,
                                                  const float* __restrict__ pbb,
                                                  const float* __restrict__ W2,
                                                  const float* __restrict__ b2,
                                                  const float* __restrict__ Wo1,
                                                  const float* __restrict__ bo1,
                                                  const float* __restrict__ Wo2,
                                                  const float* __restrict__ bo2,
                                                  float* __restrict__ out) {
    __shared__ float adjs[2][NN];          // 4 KB
    __shared__ float pbbs[2][HH];          // 2 KB
    __shared__ float ts[2][HH];            // 2 KB  (Tsum rows)
    __shared__ float buf1[2][HH];          // pred
    __shared__ float buf2[2][HH];          // h2
    __shared__ float redT[3][2][2][128];   // 6 KB  (jq partials: [jq-1][hb][r][hl])
    __shared__ float rsum_s[2];

    const int b = blockIdx.x;
    const int t = threadIdx.x;
    const int i0 = b * 2;

    if (t < 256) {
        const int f = t * 4;
        const int r = f >> 9;
        const int c = f & 511;
        *(float4*)&adjs[r][c] = *(const float4*)&adj[(i0 + r) * NN + c];
    } else if (t < 384) {
        const int f = (t - 256) * 4;
        const int r = f >> 8;
        const int c = f & 255;
        *(float4*)&pbbs[r][c] = *(const float4*)&pbb[(i0 + r) * HH + c];
    }
    __syncthreads();

    // rowsum (2 waves)
    if (t < 128) {
        const int r = t >> 6;
        const int l = t & 63;
        float s = 0.f;
        #pragma unroll
        for (int m = 0; m < 8; ++m) s += adjs[r][l + 64 * m];
        #pragma unroll
        for (int off = 32; off > 0; off >>= 1) s += __shfl_down(s, off, 64);
        if (l == 0) rsum_s[r] = s;
    }

    // T phase: jq = t>>7 (j quarter), hl = t&127; loop hb halves.
    const int jq = t >> 7;
    const int hl = t & 127;
    float acc[2][2] = {{0.f, 0.f}, {0.f, 0.f}};   // [hb][r]
    #pragma unroll
    for (int hb = 0; hb < 2; ++hb) {
        const int h = hb * 128 + hl;
        const float pb0 = pbbs[0][h];
        const float pb1 = pbbs[1][h];
        const float* pac = pa + (jq * 128) * HH + h;
        #pragma unroll 4
        for (int j = 0; j < 128; j += 4) {
            float p0 = pac[(j + 0) * HH];
            float p1 = pac[(j + 1) * HH];
            float p2 = pac[(j + 2) * HH];
            float p3 = pac[(j + 3) * HH];
            float4 A0 = *(const float4*)&adjs[0][jq * 128 + j];
            float4 A1 = *(const float4*)&adjs[1][jq * 128 + j];
            float r0 = fmaxf(p0 + pb0, 0.f);
            float r1 = fmaxf(p1 + pb0, 0.f);
            float r2 = fmaxf(p2 + pb0, 0.f);
            float r3 = fmaxf(p3 + pb0, 0.f);
            acc[hb][0] += A0.x * r0 + A0.y * r1 + A0.z * r2 + A0.w * r3;
            float q0 = fmaxf(p0 + pb1, 0.f);
            float q1 = fmaxf(p1 + pb1, 0.f);
            float q2 = fmaxf(p2 + pb1, 0.f);
            float q3 = fmaxf(p3 + pb1, 0.f);
            acc[hb][1] += A1.x * q0 + A1.y * q1 + A1.z * q2 + A1.w * q3;
        }
    }
    if (jq) {
        #pragma unroll
        for (int hb = 0; hb < 2; ++hb)
            #pragma unroll
            for (int r = 0; r < 2; ++r) redT[jq - 1][hb][r][hl] = acc[hb][r];
    }
    __syncthreads();
    if (jq == 0) {
        #pragma unroll
        for (int hb = 0; hb < 2; ++hb)
            #pragma unroll
            for (int r = 0; r < 2; ++r)
                ts[r][hb * 128 + hl] = acc[hb][r] + redT[0][hb][r][hl]
                                     + redT[1][hb][r][hl] + redT[2][hb][r][hl];
    }
    __syncthreads();

    // stage 1: pred = (ts @ W2^T + b2*rowsum) / N   (threads 0..255, k = t)
    if (t < 256) {
        const int k = t;
        const float4* w4 = (const float4*)(W2 + k * HH);
        float s0 = 0.f, s1 = 0.f;
        #pragma unroll 8
        for (int d4 = 0; d4 < HH / 4; ++d4) {
            float4 w = w4[d4];
            float4 t0 = *(const float4*)&ts[0][d4 * 4];
            float4 t1 = *(const float4*)&ts[1][d4 * 4];
            s0 += dot4(w, t0);
            s1 += dot4(w, t1);
        }
        const float bv = b2[k];
        buf1[0][k] = (s0 + bv * rsum_s[0]) * (1.0f / (float)NN);
        buf1[1][k] = (s1 + bv * rsum_s[1]) * (1.0f / (float)NN);
    }
    __syncthreads();

    // stage 2: h2 = relu(pred @ Wo1^T + bo1)
    if (t < 256) {
        const int k = t;
        const float4* w4 = (const float4*)(Wo1 + k * HH);
        float s0 = 0.f, s1 = 0.f;
        #pragma unroll 8
        for (int d4 = 0; d4 < HH / 4; ++d4) {
            float4 w = w4[d4];
            float4 t0 = *(const float4*)&buf1[0][d4 * 4];
            float4 t1 = *(const float4*)&buf1[1][d4 * 4];
            s0 += dot4(w, t0);
            s1 += dot4(w, t1);
        }
        const float bv = bo1[k];
        buf2[0][k] = fmaxf(s0 + bv, 0.f);
        buf2[1][k] = fmaxf(s1 + bv, 0.f);
    }
    __syncthreads();

    // stage 3: out = h2 @ Wo2^T + bo2
    if (t < 256) {
        const int k = t;
        const float4* w4 = (const float4*)(Wo2 + k * HH);
        float s0 = 0.f, s1 = 0.f;
        #pragma unroll 8
        for (int d4 = 0; d4 < HH / 4; ++d4) {
            float4 w = w4[d4];
            float4 t0 = *(const float4*)&buf2[0][d4 * 4];
            float4 t1 = *(const float4*)&buf2[1][d4 * 4];
            s0 += dot4(w, t0);
            s1 += dot4(w, t1);
        }
        const float bv = bo2[k];
        out[i0 * HH + k] = s0 + bv;
        out[(i0 + 1) * HH + k] = s1 + bv;
    }
}

extern "C" void kernel_launch(void* const* d_in, const int* in_sizes, int n_in,
                              void* d_out, int out_size, void* d_ws, size_t ws_size,
                              hipStream_t stream) {
    const float* x   = (const float*)d_in[0];
    const float* adj = (const float*)d_in[1];
    const float* W1  = (const float*)d_in[2];
    const float* b1  = (const float*)d_in[3];
    const float* W2  = (const float*)d_in[4];
    const float* b2  = (const float*)d_in[5];
    const float* Wo1 = (const float*)d_in[6];
    const float* bo1 = (const float*)d_in[7];
    const float* Wo2 = (const float*)d_in[8];
    const float* bo2 = (const float*)d_in[9];
    float* out = (float*)d_out;
    float* ws  = (float*)d_ws;

    float* pa  = ws;            // 512*256
    float* pbb = ws + 131072;   // 512*256

    k1_papb<<<256, 256, 0, stream>>>(x, W1, b1, pa, pbb);
    k2_rest<<<256, 512, 0, stream>>>(adj, pa, pbb, W2, b2, Wo1, bo1, Wo2, bo2, out);
}

// Round 7
// 36.770 us; speedup vs baseline: 3.9545x; 1.3664x over previous
//
#include <hip/hip_runtime.h>

#define NN 512
#define DD 128
#define HH 256

__device__ __forceinline__ float dot4(float4 a, float4 b) {
    return a.x * b.x + a.y * b.y + a.z * b.z + a.w * b.w;
}

// K1: blocks 0..255: pa = x@Wa^T, pbb = x@Wb^T + b1 (2 rows/block)
//     blocks 256..303: transpose W2/Wo1/Wo2 -> WT in ws (64x64 tiles)
__global__ __launch_bounds__(256) void k1_pre(const float* __restrict__ x,
                                              const float* __restrict__ W1,
                                              const float* __restrict__ b1,
                                              const float* __restrict__ W2,
                                              const float* __restrict__ Wo1,
                                              const float* __restrict__ Wo2,
                                              float* __restrict__ pa,
                                              float* __restrict__ pbb,
                                              float* __restrict__ wsT) {
    __shared__ float smem[64 * 68];
    const int b = blockIdx.x;
    const int t = threadIdx.x;
    if (b < 256) {
        float (*xs)[DD] = (float(*)[DD])smem;
        const int i0 = b * 2;
        if (t < 64) {
            const int f = t * 4;
            *(float4*)&xs[f >> 7][f & 127] = *(const float4*)&x[i0 * DD + f];
        }
        __syncthreads();
        const int h = t;
        const float4* w4 = (const float4*)(W1 + h * (2 * DD));
        const float4* x0 = (const float4*)&xs[0][0];
        const float4* x1 = (const float4*)&xs[1][0];
        float a0 = 0.f, a1 = 0.f, c0 = 0.f, c1 = 0.f;
        #pragma unroll 8
        for (int d4 = 0; d4 < DD / 4; ++d4) {
            float4 wa = w4[d4];
            float4 wb = w4[d4 + 32];
            float4 v0 = x0[d4];
            float4 v1 = x1[d4];
            a0 += dot4(wa, v0);
            a1 += dot4(wa, v1);
            c0 += dot4(wb, v0);
            c1 += dot4(wb, v1);
        }
        const float bb = b1[h];
        pa[i0 * HH + h] = a0;
        pa[(i0 + 1) * HH + h] = a1;
        pbb[i0 * HH + h] = c0 + bb;
        pbb[(i0 + 1) * HH + h] = c1 + bb;
    } else {
        float (*tl)[68] = (float(*)[68])smem;
        const int bb = b - 256;
        const int m = bb >> 4, tile = bb & 15;
        const float* src = (m == 0) ? W2 : (m == 1) ? Wo1 : Wo2;
        float* dst = wsT + m * (HH * HH);
        const int sr0 = (tile >> 2) * 64;   // k block in source
        const int sc0 = (tile & 3) * 64;    // h block in source
        const int rr = t >> 4;              // 0..15
        const int cc = (t & 15) * 4;
        #pragma unroll
        for (int it = 0; it < 4; ++it) {
            const int row = rr + 16 * it;
            float4 v = *(const float4*)&src[(sr0 + row) * HH + sc0 + cc];
            tl[row][cc + 0] = v.x;
            tl[row][cc + 1] = v.y;
            tl[row][cc + 2] = v.z;
            tl[row][cc + 3] = v.w;
        }
        __syncthreads();
        #pragma unroll
        for (int it = 0; it < 4; ++it) {
            const int lc = rr + 16 * it;    // local h
            float4 o;
            o.x = tl[cc + 0][lc];
            o.y = tl[cc + 1][lc];
            o.z = tl[cc + 2][lc];
            o.w = tl[cc + 3][lc];
            *(float4*)&dst[(sc0 + lc) * HH + sr0 + cc] = o;   // WT[h][k]
        }
    }
}

// K2: T + rowsum + 3 stage GEMMs, 2 rows/block, 256 blocks x 1024 threads.
__global__ __launch_bounds__(1024) void k2_rest(const float* __restrict__ adj,
                                                const float* __restrict__ pa,
                                                const float* __restrict__ pbb,
                                                const float* __restrict__ wsT,
                                                const float* __restrict__ b2,
                                                const float* __restrict__ bo1,
                                                const float* __restrict__ bo2,
                                                float* __restrict__ out) {
    __shared__ float adjs[2][NN];        // 4 KB
    __shared__ float pbbs[2][HH];        // 2 KB
    __shared__ float ts[2][HH];          // 2 KB
    __shared__ float buf1[2][HH];        // 2 KB
    __shared__ float buf2[2][HH];        // 2 KB
    __shared__ float redbuf[4096];       // 16 KB (T: [jq][hb][r][hl]; stages: [hp][r][k])
    __shared__ float rsum_s[2];

    const int b = blockIdx.x;
    const int t = threadIdx.x;
    const int i0 = b * 2;

    // stage inputs: adj rows + pbb rows
    if (t < 256) {
        const int f = t * 4;
        *(float4*)&adjs[f >> 9][f & 511] = *(const float4*)&adj[(i0 + (f >> 9)) * NN + (f & 511)];
    } else if (t < 384) {
        const int f = (t - 256) * 4;
        *(float4*)&pbbs[f >> 8][f & 255] = *(const float4*)&pbb[(i0 + (f >> 8)) * HH + (f & 255)];
    }
    __syncthreads();

    // rowsum from adjs
    if (t < 128) {
        const int r = t >> 6, l = t & 63;
        float s = 0.f;
        #pragma unroll
        for (int m = 0; m < 8; ++m) s += adjs[r][l + 64 * m];
        #pragma unroll
        for (int off = 32; off > 0; off >>= 1) s += __shfl_down(s, off, 64);
        if (l == 0) rsum_s[r] = s;
    }

    // ---- T phase: hb = t>>9, jq = (t>>7)&3, hl = t&127 ----
    {
        const int hb = t >> 9;
        const int jq = (t >> 7) & 3;
        const int hl = t & 127;
        const int h = hb * 128 + hl;
        const float pb0 = pbbs[0][h];
        const float pb1 = pbbs[1][h];
        float ac0 = 0.f, ac1 = 0.f;
        const float* pac = pa + (jq * 128) * HH + h;
        #pragma unroll 4
        for (int j = 0; j < 128; j += 4) {
            float p0 = pac[(j + 0) * HH];
            float p1 = pac[(j + 1) * HH];
            float p2 = pac[(j + 2) * HH];
            float p3 = pac[(j + 3) * HH];
            float4 A0 = *(const float4*)&adjs[0][jq * 128 + j];
            float4 A1 = *(const float4*)&adjs[1][jq * 128 + j];
            ac0 += A0.x * fmaxf(p0 + pb0, 0.f);
            ac0 += A0.y * fmaxf(p1 + pb0, 0.f);
            ac0 += A0.z * fmaxf(p2 + pb0, 0.f);
            ac0 += A0.w * fmaxf(p3 + pb0, 0.f);
            ac1 += A1.x * fmaxf(p0 + pb1, 0.f);
            ac1 += A1.y * fmaxf(p1 + pb1, 0.f);
            ac1 += A1.z * fmaxf(p2 + pb1, 0.f);
            ac1 += A1.w * fmaxf(p3 + pb1, 0.f);
        }
        redbuf[((jq * 2 + hb) * 2 + 0) * 128 + hl] = ac0;
        redbuf[((jq * 2 + hb) * 2 + 1) * 128 + hl] = ac1;
        __syncthreads();
        if (jq == 0) {
            #pragma unroll
            for (int r = 0; r < 2; ++r) {
                float s = (r == 0 ? ac0 : ac1);
                #pragma unroll
                for (int q = 1; q < 4; ++q)
                    s += redbuf[((q * 2 + hb) * 2 + r) * 128 + hl];
                ts[r][h] = s;
            }
        }
    }
    __syncthreads();

    // ---- stages: k = t&255, hp = t>>8 (4-way h split), WT coalesced ----
    const int k = t & 255;
    const int hp = t >> 8;
    const float* W2T  = wsT;
    const float* Wo1T = wsT + HH * HH;
    const float* Wo2T = wsT + 2 * HH * HH;

    // stage 1: pred = (ts @ W2T + b2*rowsum)/N -> buf1
    {
        const float* wt = W2T + (hp * 64) * HH + k;
        float a0 = 0.f, a1 = 0.f;
        #pragma unroll 8
        for (int hh = 0; hh < 64; ++hh) {
            float w = wt[hh * HH];
            a0 += w * ts[0][hp * 64 + hh];
            a1 += w * ts[1][hp * 64 + hh];
        }
        redbuf[(hp * 2 + 0) * 256 + k] = a0;
        redbuf[(hp * 2 + 1) * 256 + k] = a1;
        __syncthreads();
        if (hp == 0) {
            const float bv = b2[k];
            const float inv = 1.0f / (float)NN;
            float s0 = a0, s1 = a1;
            #pragma unroll
            for (int p = 1; p < 4; ++p) {
                s0 += redbuf[(p * 2 + 0) * 256 + k];
                s1 += redbuf[(p * 2 + 1) * 256 + k];
            }
            buf1[0][k] = (s0 + bv * rsum_s[0]) * inv;
            buf1[1][k] = (s1 + bv * rsum_s[1]) * inv;
        }
    }
    __syncthreads();

    // stage 2: h2 = relu(pred @ Wo1T + bo1) -> buf2
    {
        const float* wt = Wo1T + (hp * 64) * HH + k;
        float a0 = 0.f, a1 = 0.f;
        #pragma unroll 8
        for (int hh = 0; hh < 64; ++hh) {
            float w = wt[hh * HH];
            a0 += w * buf1[0][hp * 64 + hh];
            a1 += w * buf1[1][hp * 64 + hh];
        }
        redbuf[(hp * 2 + 0) * 256 + k] = a0;
        redbuf[(hp * 2 + 1) * 256 + k] = a1;
        __syncthreads();
        if (hp == 0) {
            const float bv = bo1[k];
            float s0 = a0, s1 = a1;
            #pragma unroll
            for (int p = 1; p < 4; ++p) {
                s0 += redbuf[(p * 2 + 0) * 256 + k];
                s1 += redbuf[(p * 2 + 1) * 256 + k];
            }
            buf2[0][k] = fmaxf(s0 + bv, 0.f);
            buf2[1][k] = fmaxf(s1 + bv, 0.f);
        }
    }
    __syncthreads();

    // stage 3: out = h2 @ Wo2T + bo2
    {
        const float* wt = Wo2T + (hp * 64) * HH + k;
        float a0 = 0.f, a1 = 0.f;
        #pragma unroll 8
        for (int hh = 0; hh < 64; ++hh) {
            float w = wt[hh * HH];
            a0 += w * buf2[0][hp * 64 + hh];
            a1 += w * buf2[1][hp * 64 + hh];
        }
        redbuf[(hp * 2 + 0) * 256 + k] = a0;
        redbuf[(hp * 2 + 1) * 256 + k] = a1;
        __syncthreads();
        if (hp == 0) {
            const float bv = bo2[k];
            float s0 = a0, s1 = a1;
            #pragma unroll
            for (int p = 1; p < 4; ++p) {
                s0 += redbuf[(p * 2 + 0) * 256 + k];
                s1 += redbuf[(p * 2 + 1) * 256 + k];
            }
            out[i0 * HH + k] = s0 + bv;
            out[(i0 + 1) * HH + k] = s1 + bv;
        }
    }
}

extern "C" void kernel_launch(void* const* d_in, const int* in_sizes, int n_in,
                              void* d_out, int out_size, void* d_ws, size_t ws_size,
                              hipStream_t stream) {
    const float* x   = (const float*)d_in[0];
    const float* adj = (const float*)d_in[1];
    const float* W1  = (const float*)d_in[2];
    const float* b1  = (const float*)d_in[3];
    const float* W2  = (const float*)d_in[4];
    const float* b2  = (const float*)d_in[5];
    const float* Wo1 = (const float*)d_in[6];
    const float* bo1 = (const float*)d_in[7];
    const float* Wo2 = (const float*)d_in[8];
    const float* bo2 = (const float*)d_in[9];
    float* out = (float*)d_out;
    float* ws  = (float*)d_ws;

    float* pa  = ws;            // 131072
    float* pbb = ws + 131072;   // 131072
    float* wsT = ws + 262144;   // 3 * 65536

    k1_pre<<<304, 256, 0, stream>>>(x, W1, b1, W2, Wo1, Wo2, pa, pbb, wsT);
    k2_rest<<<256, 1024, 0, stream>>>(adj, pa, pbb, wsT, b2, bo1, bo2, out);
}

// Round 8
// 32.617 us; speedup vs baseline: 4.4581x; 1.1273x over previous
//
#include <hip/hip_runtime.h>

#define NN 512
#define DD 128
#define HH 256

// ---------------------------------------------------------------------------
// k0: transpose W1, W2, Wo1, Wo2 (each 256x256) into ws. 64 blocks x 256 thr.
// dst[m][c][r] = src[m][r][c]
// ---------------------------------------------------------------------------
__global__ __launch_bounds__(256) void k0_tr(const float* __restrict__ W1,
                                             const float* __restrict__ W2,
                                             const float* __restrict__ Wo1,
                                             const float* __restrict__ Wo2,
                                             float* __restrict__ wsT) {
    __shared__ float tl[64][68];
    const int b = blockIdx.x;
    const int t = threadIdx.x;
    const int m = b >> 4, tile = b & 15;
    const float* src = (m == 0) ? W1 : (m == 1) ? W2 : (m == 2) ? Wo1 : Wo2;
    float* dst = wsT + m * (HH * HH);
    const int sr0 = (tile >> 2) * 64;
    const int sc0 = (tile & 3) * 64;
    const int rr = t >> 4;
    const int cc = (t & 15) * 4;
    #pragma unroll
    for (int it = 0; it < 4; ++it) {
        const int row = rr + 16 * it;
        float4 v = *(const float4*)&src[(sr0 + row) * HH + sc0 + cc];
        tl[row][cc + 0] = v.x;
        tl[row][cc + 1] = v.y;
        tl[row][cc + 2] = v.z;
        tl[row][cc + 3] = v.w;
    }
    __syncthreads();
    #pragma unroll
    for (int it = 0; it < 4; ++it) {
        const int lc = rr + 16 * it;
        float4 o;
        o.x = tl[cc + 0][lc];
        o.y = tl[cc + 1][lc];
        o.z = tl[cc + 2][lc];
        o.w = tl[cc + 3][lc];
        *(float4*)&dst[(sc0 + lc) * HH + sr0 + cc] = o;
    }
}

// ---------------------------------------------------------------------------
// k1: pa = x@Wa^T, pbb = x@Wb^T + b1, reading W1T coalesced with per-block
// stream rotation. 256 blocks x 256 threads, 2 rows/block.
// ---------------------------------------------------------------------------
__global__ __launch_bounds__(256) void k1_papb(const float* __restrict__ x,
                                               const float* __restrict__ W1T,
                                               const float* __restrict__ b1,
                                               float* __restrict__ pa,
                                               float* __restrict__ pbb) {
    __shared__ float xs[2][DD];
    const int b = blockIdx.x;
    const int t = threadIdx.x;
    const int i0 = b * 2;
    if (t < 64) {
        const int f = t * 4;
        *(float4*)&xs[f >> 7][f & 127] = *(const float4*)&x[i0 * DD + f];
    }
    __syncthreads();
    const float* wt = W1T + t;            // W1T[c][h=t], lane-coalesced
    const int crot = (b * 8) & 127;
    float pe0 = 0.f, po0 = 0.f, pe1 = 0.f, po1 = 0.f;
    float qe0 = 0.f, qo0 = 0.f, qe1 = 0.f, qo1 = 0.f;
    #pragma unroll 2
    for (int cc0 = 0; cc0 < 128; cc0 += 8) {
        const int c = (cc0 + crot) & 127;
        float w0 = wt[(c + 0) * HH], w1 = wt[(c + 1) * HH];
        float w2 = wt[(c + 2) * HH], w3 = wt[(c + 3) * HH];
        float w4 = wt[(c + 4) * HH], w5 = wt[(c + 5) * HH];
        float w6 = wt[(c + 6) * HH], w7 = wt[(c + 7) * HH];
        float v0 = wt[(128 + c + 0) * HH], v1 = wt[(128 + c + 1) * HH];
        float v2 = wt[(128 + c + 2) * HH], v3 = wt[(128 + c + 3) * HH];
        float v4 = wt[(128 + c + 4) * HH], v5 = wt[(128 + c + 5) * HH];
        float v6 = wt[(128 + c + 6) * HH], v7 = wt[(128 + c + 7) * HH];
        float4 x0a = *(const float4*)&xs[0][c];
        float4 x0b = *(const float4*)&xs[0][c + 4];
        float4 x1a = *(const float4*)&xs[1][c];
        float4 x1b = *(const float4*)&xs[1][c + 4];
        pe0 += w0 * x0a.x + w1 * x0a.y + w2 * x0a.z + w3 * x0a.w;
        po0 += w4 * x0b.x + w5 * x0b.y + w6 * x0b.z + w7 * x0b.w;
        pe1 += w0 * x1a.x + w1 * x1a.y + w2 * x1a.z + w3 * x1a.w;
        po1 += w4 * x1b.x + w5 * x1b.y + w6 * x1b.z + w7 * x1b.w;
        qe0 += v0 * x0a.x + v1 * x0a.y + v2 * x0a.z + v3 * x0a.w;
        qo0 += v4 * x0b.x + v5 * x0b.y + v6 * x0b.z + v7 * x0b.w;
        qe1 += v0 * x1a.x + v1 * x1a.y + v2 * x1a.z + v3 * x1a.w;
        qo1 += v4 * x1b.x + v5 * x1b.y + v6 * x1b.z + v7 * x1b.w;
    }
    const float bb = b1[t];
    pa[i0 * HH + t] = pe0 + po0;
    pa[(i0 + 1) * HH + t] = pe1 + po1;
    pbb[i0 * HH + t] = qe0 + qo0 + bb;
    pbb[(i0 + 1) * HH + t] = qe1 + qo1 + bb;
}

// ---------------------------------------------------------------------------
// k2: T + rowsum + 3 stage GEMMs, 2 rows/block, 256 blocks x 1024 threads.
// Per-block rotated streams + deep ILP.
// ---------------------------------------------------------------------------
__device__ __forceinline__ void stage_dot8(const float* __restrict__ wt,
                                           const float* in0, const float* in1,
                                           int hrot, float& A0, float& A1) {
    float e0 = 0.f, o0 = 0.f, e1 = 0.f, o1 = 0.f;
    #pragma unroll 2
    for (int hh0 = 0; hh0 < 64; hh0 += 8) {
        const int hh = (hh0 + hrot) & 63;
        float w0 = wt[(hh + 0) * HH], w1 = wt[(hh + 1) * HH];
        float w2 = wt[(hh + 2) * HH], w3 = wt[(hh + 3) * HH];
        float w4 = wt[(hh + 4) * HH], w5 = wt[(hh + 5) * HH];
        float w6 = wt[(hh + 6) * HH], w7 = wt[(hh + 7) * HH];
        float4 t0a = *(const float4*)&in0[hh];
        float4 t0b = *(const float4*)&in0[hh + 4];
        float4 t1a = *(const float4*)&in1[hh];
        float4 t1b = *(const float4*)&in1[hh + 4];
        e0 += w0 * t0a.x + w1 * t0a.y + w2 * t0a.z + w3 * t0a.w;
        o0 += w4 * t0b.x + w5 * t0b.y + w6 * t0b.z + w7 * t0b.w;
        e1 += w0 * t1a.x + w1 * t1a.y + w2 * t1a.z + w3 * t1a.w;
        o1 += w4 * t1b.x + w5 * t1b.y + w6 * t1b.z + w7 * t1b.w;
    }
    A0 = e0 + o0;
    A1 = e1 + o1;
}

__global__ __launch_bounds__(1024) void k2_rest(const float* __restrict__ adj,
                                                const float* __restrict__ pa,
                                                const float* __restrict__ pbb,
                                                const float* __restrict__ wsT,
                                                const float* __restrict__ b2,
                                                const float* __restrict__ bo1,
                                                const float* __restrict__ bo2,
                                                float* __restrict__ out) {
    __shared__ float adjs[2][NN];
    __shared__ float pbbs[2][HH];
    __shared__ float ts[2][HH];
    __shared__ float buf1[2][HH];
    __shared__ float buf2[2][HH];
    __shared__ float redbuf[4096];
    __shared__ float rsum_s[2];

    const int b = blockIdx.x;
    const int t = threadIdx.x;
    const int i0 = b * 2;

    if (t < 256) {
        const int f = t * 4;
        *(float4*)&adjs[f >> 9][f & 511] = *(const float4*)&adj[(i0 + (f >> 9)) * NN + (f & 511)];
    } else if (t < 384) {
        const int f = (t - 256) * 4;
        *(float4*)&pbbs[f >> 8][f & 255] = *(const float4*)&pbb[(i0 + (f >> 8)) * HH + (f & 255)];
    }
    __syncthreads();

    if (t < 128) {
        const int r = t >> 6, l = t & 63;
        float s = 0.f;
        #pragma unroll
        for (int m = 0; m < 8; ++m) s += adjs[r][l + 64 * m];
        #pragma unroll
        for (int off = 32; off > 0; off >>= 1) s += __shfl_down(s, off, 64);
        if (l == 0) rsum_s[r] = s;
    }

    // ---- T phase ----
    {
        const int hb = t >> 9;
        const int jq = (t >> 7) & 3;
        const int hl = t & 127;
        const int h = hb * 128 + hl;
        const float pb0 = pbbs[0][h];
        const float pb1 = pbbs[1][h];
        const float* pac = pa + (jq * 128) * HH + h;
        const float* arow0 = &adjs[0][jq * 128];
        const float* arow1 = &adjs[1][jq * 128];
        const int jrot = (b * 8) & 127;
        float ae0 = 0.f, ao0 = 0.f, ae1 = 0.f, ao1 = 0.f;
        #pragma unroll 2
        for (int jj0 = 0; jj0 < 128; jj0 += 8) {
            const int j = (jj0 + jrot) & 127;
            float p0 = pac[(j + 0) * HH], p1 = pac[(j + 1) * HH];
            float p2 = pac[(j + 2) * HH], p3 = pac[(j + 3) * HH];
            float p4 = pac[(j + 4) * HH], p5 = pac[(j + 5) * HH];
            float p6 = pac[(j + 6) * HH], p7 = pac[(j + 7) * HH];
            float4 A0a = *(const float4*)&arow0[j];
            float4 A0b = *(const float4*)&arow0[j + 4];
            float4 A1a = *(const float4*)&arow1[j];
            float4 A1b = *(const float4*)&arow1[j + 4];
            float r0 = fmaxf(p0 + pb0, 0.f), r1 = fmaxf(p1 + pb0, 0.f);
            float r2 = fmaxf(p2 + pb0, 0.f), r3 = fmaxf(p3 + pb0, 0.f);
            float r4 = fmaxf(p4 + pb0, 0.f), r5 = fmaxf(p5 + pb0, 0.f);
            float r6 = fmaxf(p6 + pb0, 0.f), r7 = fmaxf(p7 + pb0, 0.f);
            ae0 += A0a.x * r0 + A0a.y * r1 + A0a.z * r2 + A0a.w * r3;
            ao0 += A0b.x * r4 + A0b.y * r5 + A0b.z * r6 + A0b.w * r7;
            float s0 = fmaxf(p0 + pb1, 0.f), s1 = fmaxf(p1 + pb1, 0.f);
            float s2 = fmaxf(p2 + pb1, 0.f), s3 = fmaxf(p3 + pb1, 0.f);
            float s4 = fmaxf(p4 + pb1, 0.f), s5 = fmaxf(p5 + pb1, 0.f);
            float s6 = fmaxf(p6 + pb1, 0.f), s7 = fmaxf(p7 + pb1, 0.f);
            ae1 += A1a.x * s0 + A1a.y * s1 + A1a.z * s2 + A1a.w * s3;
            ao1 += A1b.x * s4 + A1b.y * s5 + A1b.z * s6 + A1b.w * s7;
        }
        const float ac0 = ae0 + ao0;
        const float ac1 = ae1 + ao1;
        redbuf[((jq * 2 + hb) * 2 + 0) * 128 + hl] = ac0;
        redbuf[((jq * 2 + hb) * 2 + 1) * 128 + hl] = ac1;
        __syncthreads();
        if (jq == 0) {
            #pragma unroll
            for (int r = 0; r < 2; ++r) {
                float s = (r == 0 ? ac0 : ac1);
                #pragma unroll
                for (int q = 1; q < 4; ++q)
                    s += redbuf[((q * 2 + hb) * 2 + r) * 128 + hl];
                ts[r][h] = s;
            }
        }
    }
    __syncthreads();

    const int k = t & 255;
    const int hp = t >> 8;
    const int hrot = (b * 8) & 63;
    const float* W2T  = wsT + 1 * (HH * HH);
    const float* Wo1T = wsT + 2 * (HH * HH);
    const float* Wo2T = wsT + 3 * (HH * HH);

    // stage 1: pred = (ts @ W2T + b2*rowsum)/N -> buf1
    {
        float a0, a1;
        stage_dot8(W2T + (hp * 64) * HH + k, &ts[0][hp * 64], &ts[1][hp * 64], hrot, a0, a1);
        redbuf[(hp * 2 + 0) * 256 + k] = a0;
        redbuf[(hp * 2 + 1) * 256 + k] = a1;
        __syncthreads();
        if (hp == 0) {
            const float bv = b2[k];
            const float inv = 1.0f / (float)NN;
            float s0 = a0, s1 = a1;
            #pragma unroll
            for (int p = 1; p < 4; ++p) {
                s0 += redbuf[(p * 2 + 0) * 256 + k];
                s1 += redbuf[(p * 2 + 1) * 256 + k];
            }
            buf1[0][k] = (s0 + bv * rsum_s[0]) * inv;
            buf1[1][k] = (s1 + bv * rsum_s[1]) * inv;
        }
    }
    __syncthreads();

    // stage 2: h2 = relu(pred @ Wo1T + bo1) -> buf2
    {
        float a0, a1;
        stage_dot8(Wo1T + (hp * 64) * HH + k, &buf1[0][hp * 64], &buf1[1][hp * 64], hrot, a0, a1);
        redbuf[(hp * 2 + 0) * 256 + k] = a0;
        redbuf[(hp * 2 + 1) * 256 + k] = a1;
        __syncthreads();
        if (hp == 0) {
            const float bv = bo1[k];
            float s0 = a0, s1 = a1;
            #pragma unroll
            for (int p = 1; p < 4; ++p) {
                s0 += redbuf[(p * 2 + 0) * 256 + k];
                s1 += redbuf[(p * 2 + 1) * 256 + k];
            }
            buf2[0][k] = fmaxf(s0 + bv, 0.f);
            buf2[1][k] = fmaxf(s1 + bv, 0.f);
        }
    }
    __syncthreads();

    // stage 3: out = h2 @ Wo2T + bo2
    {
        float a0, a1;
        stage_dot8(Wo2T + (hp * 64) * HH + k, &buf2[0][hp * 64], &buf2[1][hp * 64], hrot, a0, a1);
        redbuf[(hp * 2 + 0) * 256 + k] = a0;
        redbuf[(hp * 2 + 1) * 256 + k] = a1;
        __syncthreads();
        if (hp == 0) {
            const float bv = bo2[k];
            float s0 = a0, s1 = a1;
            #pragma unroll
            for (int p = 1; p < 4; ++p) {
                s0 += redbuf[(p * 2 + 0) * 256 + k];
                s1 += redbuf[(p * 2 + 1) * 256 + k];
            }
            out[i0 * HH + k] = s0 + bv;
            out[(i0 + 1) * HH + k] = s1 + bv;
        }
    }
}

extern "C" void kernel_launch(void* const* d_in, const int* in_sizes, int n_in,
                              void* d_out, int out_size, void* d_ws, size_t ws_size,
                              hipStream_t stream) {
    const float* x   = (const float*)d_in[0];
    const float* adj = (const float*)d_in[1];
    const float* W1  = (const float*)d_in[2];
    const float* b1  = (const float*)d_in[3];
    const float* W2  = (const float*)d_in[4];
    const float* b2  = (const float*)d_in[5];
    const float* Wo1 = (const float*)d_in[6];
    const float* bo1 = (const float*)d_in[7];
    const float* Wo2 = (const float*)d_in[8];
    const float* bo2 = (const float*)d_in[9];
    float* out = (float*)d_out;
    float* ws  = (float*)d_ws;

    float* wsT = ws;            // 4 * 65536: W1T, W2T, Wo1T, Wo2T
    float* pa  = ws + 262144;   // 131072
    float* pbb = ws + 393216;   // 131072

    k0_tr<<<64, 256, 0, stream>>>(W1, W2, Wo1, Wo2, wsT);
    k1_papb<<<256, 256, 0, stream>>>(x, wsT, b1, pa, pbb);
    k2_rest<<<256, 1024, 0, stream>>>(adj, pa, pbb, wsT, b2, bo1, bo2, out);
}